// Round 8
// baseline (2079.864 us; speedup 1.0000x reference)
//
#include <hip/hip_runtime.h>
#include <stdint.h>

#define NB 128
#define NT 2048
#define NI 128
#define NH 1024
#define NO 128

typedef float f32x4 __attribute__((ext_vector_type(4)));
typedef float f32x16 __attribute__((ext_vector_type(16)));

// ---------------------------------------------------------------------------
// W2P: pair-transpose W2 [O][H] -> W2P [H][64] of float2 {W2[j][k], W2[j+64][k]}
// ---------------------------------------------------------------------------
__global__ __launch_bounds__(256) void w2p_kernel(
    const float* __restrict__ W2, float2* __restrict__ W2P)
{
    const int idx = blockIdx.x * 256 + threadIdx.x;  // 0..65535
    const int k = idx >> 6;                          // 0..1023
    const int j = idx & 63;                          // 0..63
    W2P[idx] = make_float2(W2[(size_t)j * NH + k], W2[(size_t)(j + 64) * NH + k]);
}

// Pin one weight quad in VGPRs (asm defs cannot be rematerialized).
#define WL(I, OFF)                                                        \
    asm volatile("global_load_dwordx4 %0, %1, off offset:" #OFF          \
                 : "=v"(w[I]) : "v"(wp))

// 16 FMAs: weight quads w[I0..I0+3] (k = 4*I0 .. 4*I0+15 within the k-half)
// against one 16-float SGPR x vector. Order identical to R1/R2/R4/R5
// (absmax stayed 0.0): acc index = k & 3.
#define XF4(XV, I0)                                                       \
    do {                                                                  \
        a0 = fmaf(w[I0 + 0].x, XV[0],  a0);                               \
        a1 = fmaf(w[I0 + 0].y, XV[1],  a1);                               \
        a2 = fmaf(w[I0 + 0].z, XV[2],  a2);                               \
        a3 = fmaf(w[I0 + 0].w, XV[3],  a3);                               \
        a0 = fmaf(w[I0 + 1].x, XV[4],  a0);                               \
        a1 = fmaf(w[I0 + 1].y, XV[5],  a1);                               \
        a2 = fmaf(w[I0 + 1].z, XV[6],  a2);                               \
        a3 = fmaf(w[I0 + 1].w, XV[7],  a3);                               \
        a0 = fmaf(w[I0 + 2].x, XV[8],  a0);                               \
        a1 = fmaf(w[I0 + 2].y, XV[9],  a1);                               \
        a2 = fmaf(w[I0 + 2].z, XV[10], a2);                               \
        a3 = fmaf(w[I0 + 2].w, XV[11], a3);                               \
        a0 = fmaf(w[I0 + 3].x, XV[12], a0);                               \
        a1 = fmaf(w[I0 + 3].y, XV[13], a1);                               \
        a2 = fmaf(w[I0 + 3].z, XV[14], a2);                               \
        a3 = fmaf(w[I0 + 3].w, XV[15], a3);                               \
    } while (0)

// ---------------------------------------------------------------------------
// Phase A: fused GEMM1 + LIF1.
// grid = 1024 (128 b x 8 htiles of 128 h), block = 256 = 4 waves:
//   wave wv -> (khalf = wv>>1, hhalf = wv&1); lane owns h, k-range khalf*64..+63.
// KEY CHANGE vs R5: __launch_bounds__(256, 2) -> 256-VGPR budget. Every
// previous spill happened under a 128-VGPR cap ((256,4) or (512,2)) or under
// R2's extra 128-reg x pressure. Here: 64 pinned w floats + SGPR-resident x
// (SMEM s_load_dwordx16) + ~20 misc regs, under a 256 cap.
// Cross-k-half reduce via 2-slot LDS parity, one barrier/t. LIF+ballot on kh0.
// ---------------------------------------------------------------------------
__global__ __launch_bounds__(256, 2) void snn_phaseA(
    const float* __restrict__ x, const float* __restrict__ W1,
    const float* __restrict__ b1, uint64_t* __restrict__ s1bits)
{
    const int b = blockIdx.x >> 3;
    const int htile = blockIdx.x & 7;
    const int wv = threadIdx.x >> 6;
    const int lane = threadIdx.x & 63;
    const int kh = __builtin_amdgcn_readfirstlane(wv >> 1);   // 0/1
    const int hhalf = __builtin_amdgcn_readfirstlane(wv & 1); // 0/1
    const int hl = hhalf * 64 + lane;     // 0..127 within tile
    const int h = htile * 128 + hl;

    f32x4 w[16];
    const float* wp = W1 + (size_t)h * NI + kh * 64;
    WL(0, 0);    WL(1, 16);   WL(2, 32);   WL(3, 48);
    WL(4, 64);   WL(5, 80);   WL(6, 96);   WL(7, 112);
    WL(8, 128);  WL(9, 144);  WL(10, 160); WL(11, 176);
    WL(12, 192); WL(13, 208); WL(14, 224); WL(15, 240);
    asm volatile("s_waitcnt vmcnt(0)"
                 : "+v"(w[0]), "+v"(w[1]), "+v"(w[2]), "+v"(w[3]),
                   "+v"(w[4]), "+v"(w[5]), "+v"(w[6]), "+v"(w[7]),
                   "+v"(w[8]), "+v"(w[9]), "+v"(w[10]), "+v"(w[11]),
                   "+v"(w[12]), "+v"(w[13]), "+v"(w[14]), "+v"(w[15])
                 :
                 : "memory");
    __builtin_amdgcn_sched_barrier(0);

    const float bias = b1[h];
    __shared__ float red[2][128];

    const float* __restrict__ xb = x + (size_t)b * NT * NI + kh * 64;
    uint64_t* s1w = s1bits + (size_t)b * (NH / 64) + htile * 2 + hhalf;

    float v = 0.0f;
#pragma unroll 1
    for (int t = 0; t < NT; ++t) {
        const float* xr = xb + (size_t)t * NI;  // wave-uniform -> SGPR pair
        f32x16 x0, x1, x2, x3;
        asm volatile("s_load_dwordx16 %0, %1, 0x0"  : "=s"(x0) : "s"(xr));
        asm volatile("s_load_dwordx16 %0, %1, 0x40" : "=s"(x1) : "s"(xr));
        asm volatile("s_load_dwordx16 %0, %1, 0x80" : "=s"(x2) : "s"(xr));
        asm volatile("s_load_dwordx16 %0, %1, 0xc0" : "=s"(x3) : "s"(xr));
        asm volatile("s_waitcnt lgkmcnt(0)"
                     : "+s"(x0), "+s"(x1), "+s"(x2), "+s"(x3));
        __builtin_amdgcn_sched_barrier(0);

        float a0 = 0.f, a1 = 0.f, a2 = 0.f, a3 = 0.f;
        XF4(x0, 0);
        XF4(x1, 4);
        XF4(x2, 8);
        XF4(x3, 12);
        const float partial = (a0 + a1) + (a2 + a3);

        if (kh) red[t & 1][hl] = partial;
        __syncthreads();
        if (!kh) {
            const float h1 = partial + red[t & 1][hl] + bias;
            v = fmaf(h1 - v, 0.5f, v);  // v += (h1 - v)/tau, tau = 2
            const bool sp = (v >= 1.0f);
            v = sp ? 0.0f : v;
            const unsigned long long m = __ballot(sp);
            if (lane == 0) *s1w = (uint64_t)m;
        }
        s1w += NB * (NH / 64);
        // red[t&1] is re-written at t+2, after barrier(t+1): safe (R1/R5-proven).
    }
}

// ---------------------------------------------------------------------------
// Phase B: sparse GEMM2. One wave per m = t*128+b row; lane covers o = lane
// and o+64. Scalar ff1 loop over 16 mask words; per active k one coalesced
// dwordx2 of W2P[k]. Sparse sum (ascending k) == dense sum exactly.
// ---------------------------------------------------------------------------
__global__ __launch_bounds__(256, 4) void snn_phaseB(
    const uint64_t* __restrict__ s1bits, const float2* __restrict__ W2P,
    float* __restrict__ h2)
{
    const int wv = threadIdx.x >> 6;
    const int lane = threadIdx.x & 63;
    const size_t m = (size_t)blockIdx.x * 4 + wv;  // 0..262143

    const uint64_t* __restrict__ sb = s1bits + m * (NH / 64);
    float a0 = 0.f, a1 = 0.f;

#pragma unroll 1
    for (int wd = 0; wd < NH / 64; ++wd) {
        const uint64_t m64 = sb[wd];
        const uint32_t mlo = (uint32_t)__builtin_amdgcn_readfirstlane((int)(uint32_t)m64);
        const uint32_t mhi = (uint32_t)__builtin_amdgcn_readfirstlane((int)(uint32_t)(m64 >> 32));
        uint64_t msk = ((uint64_t)mhi << 32) | mlo;
        while (msk) {
            const int i = __builtin_ctzll(msk);
            msk &= (msk - 1);
            const size_t k = ((size_t)wd << 6) + i;
            const float2 ww = W2P[k * 64 + lane];
            a0 += ww.x;
            a1 += ww.y;
        }
    }
    h2[m * NO + lane] = a0;
    h2[m * NO + 64 + lane] = a1;
}

// ---------------------------------------------------------------------------
// Phase D: LIF2 scan + decision-window count. 256 blocks of 64 threads,
// unroll 16 for deep load pipelining; lanes <-> consecutive o (coalesced).
// ---------------------------------------------------------------------------
__global__ __launch_bounds__(64) void snn_phaseD(
    const float* __restrict__ h2, const float* __restrict__ b2,
    float* __restrict__ out)
{
    const int idx = blockIdx.x * 64 + threadIdx.x;  // 0..16383
    const int b = idx >> 7;
    const int o = idx & 127;
    const float bias = b2[o];

    const float* __restrict__ p = h2 + (size_t)b * NO + o;
    float v = 0.f, c = 0.f;
#pragma unroll 16
    for (int t = 0; t < NT; ++t) {
        const float hh = p[(size_t)t * NB * NO] + bias;
        v = fmaf(hh - v, 0.5f, v);
        const bool s = (v >= 1.0f);
        v = s ? 0.f : v;
        if (t >= NT / 2) c += s ? 1.f : 0.f;
    }
    out[idx] = c;
}

extern "C" void kernel_launch(void* const* d_in, const int* in_sizes, int n_in,
                              void* d_out, int out_size, void* d_ws,
                              size_t ws_size, hipStream_t stream)
{
    const float* x  = (const float*)d_in[0];
    const float* W1 = (const float*)d_in[1];
    const float* b1 = (const float*)d_in[2];
    const float* W2 = (const float*)d_in[3];
    const float* b2 = (const float*)d_in[4];
    float* out = (float*)d_out;

    // ws layout: [s1bits 33.55 MB][W2P 0.52 MB][h2 134.2 MB]
    uint8_t* ws = (uint8_t*)d_ws;
    uint64_t* s1bits = (uint64_t*)ws;
    float2* W2P = (float2*)(ws + (size_t)NT * NB * (NH / 64) * 8);
    float* h2 = (float*)(ws + (size_t)NT * NB * (NH / 64) * 8 +
                         (size_t)NH * 64 * sizeof(float2));

    w2p_kernel<<<dim3((NH * 64) / 256), dim3(256), 0, stream>>>(W2, W2P);
    snn_phaseA<<<dim3(NB * 8), dim3(256), 0, stream>>>(x, W1, b1, s1bits);
    snn_phaseB<<<dim3((NT * NB) / 4), dim3(256), 0, stream>>>(s1bits, W2P, h2);
    snn_phaseD<<<dim3(256), dim3(64), 0, stream>>>(h2, b2, out);
}